// Round 4
// baseline (100.455 us; speedup 1.0000x reference)
//
#include <hip/hip_runtime.h>
#include <math.h>

#define NB   4
#define NH   16
#define NT   4096
#define ND   64
#define NP   256
#define NREG 64
#define RPOS 4
#define CHUNKS 16          // 256-token chunks per (b,h); 4 waves x 64 tokens each

// log2(10000) / 32  (inv_freq[j] = 10000^(-2j/64))
#define INVF_LOG2 0.4152410118609203f
// 0.125 (1/sqrt(64)) * log2(e): fold into q so score feeds exp2 directly
#define QSCALE 0.18033688011112042f

#define PSTRIDE 260        // per-(b,h,region) partial: l[4] then acc[4][64]
#define PARTIAL_FLOATS (NB * NH * NREG * PSTRIDE)   // 4.26 MB

// ---------------- kernel A: region boundaries (lower_bound table) -----------
// bound[b][v] = first index i with regions[b][i] >= v   (v in 0..65)
__global__ void seg_kernel(const int* __restrict__ regions, int* __restrict__ bound) {
    const int b = blockIdx.x;
    const int* rb = regions + b * NT;
    int* bb = bound + b * 66;
    if (threadIdx.x < 66) bb[threadIdx.x] = NT;
    __syncthreads();
    for (int i = threadIdx.x; i < NT; i += blockDim.x) {
        const int r  = rb[i];
        const int rp = (i == 0) ? -1 : rb[i - 1];
        for (int v = rp + 1; v <= r; ++v) bb[v] = i;   // sorted -> unique writer
    }
}

// ---------------- kernel B: streaming partial accumulation ------------------
__global__ __launch_bounds__(256) void stream_kernel(
    const float* __restrict__ q,
    const float* __restrict__ k,
    const float* __restrict__ v,
    const int*   __restrict__ regions,
    const int*   __restrict__ bound,
    float*       __restrict__ partial)
{
    const int tid  = threadIdx.x;
    const int wave = tid >> 6;
    const int lane = tid & 63;
    const int grp  = lane >> 3;     // 0..7 : token within 8-token iter
    const int li   = lane & 7;      // 0..7 : dim chunk (8 floats)
    const int d0   = li << 3;

    const int c = blockIdx.x & (CHUNKS - 1);
    const int h = (blockIdx.x >> 4) & (NH - 1);
    const int b = blockIdx.x >> 8;

    int       t0 = (c << 8) + (wave << 6);   // this wave's 64-token span
    const int t1 = t0 + 64;

    const int* rb = regions + b * NT;
    const int* bb = bound + b * 66;
    const size_t bh = (size_t)(b * NH + h);
    const float* kb = k + bh * (size_t)(NT * ND);
    const float* vb = v + bh * (size_t)(NT * ND);
    const float* qb = q + bh * (size_t)(NP * ND);
    float* pbase = partial + (bh * NREG) * PSTRIDE;

    // per-lane frequencies (dims d0..d0+7, freq index j = d mod 32)
    float frq[8];
    #pragma unroll
    for (int i = 0; i < 8; ++i)
        frq[i] = exp2f(-INVF_LOG2 * (float)(((li & 3) << 3) + i));
    const float sgn = (li >= 4) ? 1.f : -1.f;

    while (t0 < t1) {
        const int r = rb[t0];
        if (r == 0) { t0 = min(t1, bb[1]); continue; }   // region-0 tokens: skip
        const int s       = bb[r];
        const int e       = bb[r + 1];
        const int seg_end = min(e, t1);

        // q for the region's 4 pools, pre-scaled
        const int p0 = (r - 1) << 2;
        float qs[4][8];
        #pragma unroll
        for (int p = 0; p < 4; ++p) {
            const float4 qa = *(const float4*)(qb + (size_t)(p0 + p) * ND + d0);
            const float4 qc = *(const float4*)(qb + (size_t)(p0 + p) * ND + d0 + 4);
            qs[p][0] = qa.x * QSCALE; qs[p][1] = qa.y * QSCALE;
            qs[p][2] = qa.z * QSCALE; qs[p][3] = qa.w * QSCALE;
            qs[p][4] = qc.x * QSCALE; qs[p][5] = qc.y * QSCALE;
            qs[p][6] = qc.z * QSCALE; qs[p][7] = qc.w * QSCALE;
        }

        float l[4] = {0.f, 0.f, 0.f, 0.f};
        float acc[4][8];
        #pragma unroll
        for (int p = 0; p < 4; ++p)
            #pragma unroll
            for (int i = 0; i < 8; ++i) acc[p][i] = 0.f;

        const int n     = seg_end - t0;
        const int iters = (n + 7) >> 3;
        for (int it = 0; it < iters; ++it) {
            const int  t     = t0 + (it << 3) + grp;
            const bool valid = t < seg_end;
            const int  tt    = valid ? t : t0;          // clamp to a live row
            const float* kp = kb + (size_t)tt * ND + d0;
            const float* vp = vb + (size_t)tt * ND + d0;
            const float4 ka  = *(const float4*)kp;
            const float4 kc  = *(const float4*)(kp + 4);
            const float4 va  = *(const float4*)vp;
            const float4 vc  = *(const float4*)(vp + 4);
            float kx[8] = {ka.x, ka.y, ka.z, ka.w, kc.x, kc.y, kc.z, kc.w};
            const float vx[8] = {va.x, va.y, va.z, va.w, vc.x, vc.y, vc.z, vc.w};

            const float pos = (float)(tt - s + RPOS);
            float pd0 = 0.f, pd1 = 0.f, pd2 = 0.f, pd3 = 0.f;
            #pragma unroll
            for (int i = 0; i < 8; ++i) {
                const float ang = pos * frq[i];
                float sa, ca;
                __sincosf(ang, &sa, &ca);
                const float o  = __shfl_xor(kx[i], 4);  // paired half (d ^ 32)
                const float rk = kx[i] * ca + sgn * o * sa;
                pd0 = fmaf(rk, qs[0][i], pd0);
                pd1 = fmaf(rk, qs[1][i], pd1);
                pd2 = fmaf(rk, qs[2][i], pd2);
                pd3 = fmaf(rk, qs[3][i], pd3);
            }
            float pds[4] = {pd0, pd1, pd2, pd3};
            #pragma unroll
            for (int p = 0; p < 4; ++p) {
                float pd = pds[p];
                pd += __shfl_xor(pd, 1);
                pd += __shfl_xor(pd, 2);
                pd += __shfl_xor(pd, 4);
                const float w = valid ? exp2f(pd) : 0.f;
                l[p] += w;
                #pragma unroll
                for (int i = 0; i < 8; ++i) acc[p][i] = fmaf(w, vx[i], acc[p][i]);
            }
        }

        // reduce the 8 token-groups' partials across the wave
        #pragma unroll
        for (int m = 8; m <= 32; m <<= 1) {
            #pragma unroll
            for (int p = 0; p < 4; ++p) {
                l[p] += __shfl_xor(l[p], m);
                #pragma unroll
                for (int i = 0; i < 8; ++i) acc[p][i] += __shfl_xor(acc[p][i], m);
            }
        }

        float* pr = pbase + (size_t)(r - 1) * PSTRIDE;
        if (grp == 0) {
            if (li < 4) atomicAdd(pr + li, l[li]);
            #pragma unroll
            for (int p = 0; p < 4; ++p)
                #pragma unroll
                for (int i = 0; i < 8; ++i)
                    atomicAdd(pr + 4 + p * ND + d0 + i, acc[p][i]);
        }
        t0 = seg_end;
    }
}

// ---------------- kernel C: normalize -> out --------------------------------
__global__ __launch_bounds__(256) void final_kernel(
    const float* __restrict__ partial,
    const float* __restrict__ v,
    float*       __restrict__ out)
{
    const int idx = blockIdx.x * 256 + threadIdx.x;   // one float4 of out
    const int d4 = idx & 15;
    const int p  = (idx >> 4) & (NP - 1);
    const int h  = (idx >> 12) & (NH - 1);
    const int b  = idx >> 16;
    const int r  = p >> 2;

    const size_t bh = (size_t)(b * NH + h);
    const float* pr = partial + (bh * NREG + r) * PSTRIDE;
    const float l = pr[p & 3];
    float4 o;
    if (l != 0.f) {
        const float inv = 1.f / l;
        const float4 a = *(const float4*)(pr + 4 + (p & 3) * ND + (d4 << 2));
        o = make_float4(a.x * inv, a.y * inv, a.z * inv, a.w * inv);
    } else {
        // empty region: softmax over all -1e30 -> uniform mean of v over T
        const float* vb = v + bh * (size_t)(NT * ND) + (d4 << 2);
        float sx = 0.f, sy = 0.f, sz = 0.f, sw = 0.f;
        for (int t = 0; t < NT; ++t) {
            const float4 vv = *(const float4*)(vb + (size_t)t * ND);
            sx += vv.x; sy += vv.y; sz += vv.z; sw += vv.w;
        }
        const float inv = 1.f / (float)NT;
        o = make_float4(sx * inv, sy * inv, sz * inv, sw * inv);
    }
    *(float4*)(out + (bh * NP + p) * ND + (d4 << 2)) = o;
}

extern "C" void kernel_launch(void* const* d_in, const int* in_sizes, int n_in,
                              void* d_out, int out_size, void* d_ws, size_t ws_size,
                              hipStream_t stream) {
    (void)in_sizes; (void)n_in; (void)ws_size; (void)out_size;
    const float* q       = (const float*)d_in[0];
    const float* k       = (const float*)d_in[1];
    const float* v       = (const float*)d_in[2];
    const int*   regions = (const int*)d_in[3];
    // d_in[4] t_mask, d_in[5] n_mask all-true; d_in[6] max_n == 64
    float* out     = (float*)d_out;
    float* partial = (float*)d_ws;                       // 4.26 MB
    int*   bound   = (int*)((float*)d_ws + PARTIAL_FLOATS); // 4 x 66 ints

    hipMemsetAsync(partial, 0, (size_t)PARTIAL_FLOATS * sizeof(float), stream);
    seg_kernel<<<dim3(NB), 1024, 0, stream>>>(regions, bound);
    stream_kernel<<<dim3(NB * NH * CHUNKS), 256, 0, stream>>>(q, k, v, regions, bound, partial);
    final_kernel<<<dim3((NB * NH * NP * ND / 4) / 256), 256, 0, stream>>>(partial, v, out);
}

// Round 5
// 35.120 us; speedup vs baseline: 2.8604x; 2.8604x over previous
//
#include <hip/hip_runtime.h>
#include <math.h>

#define NB   4
#define NH   16
#define NT   4096
#define ND   64
#define NP   256
#define NREG 64
#define RPOS 4

// log2(10000) / 32  (inv_freq[j] = 10000^(-2j/64))
#define INVF_LOG2 0.4152410118609203f
// 0.125 (1/sqrt(64)) * log2(e): fold into q so score feeds exp2 directly
#define QSCALE 0.18033688011112042f

// ---------------- kernel A: region boundaries (lower_bound table) -----------
// bound[b][v] = first index i with regions[b][i] >= v   (v in 0..65)
__global__ void seg_kernel(const int* __restrict__ regions, int* __restrict__ bound) {
    const int b = blockIdx.x;
    const int* rb = regions + b * NT;
    int* bb = bound + b * 66;
    if (threadIdx.x < 66) bb[threadIdx.x] = NT;
    __syncthreads();
    for (int i = threadIdx.x; i < NT; i += blockDim.x) {
        const int r  = rb[i];
        const int rp = (i == 0) ? -1 : rb[i - 1];
        for (int v = rp + 1; v <= r; ++v) bb[v] = i;   // sorted -> unique writer
    }
}

// ---------------- kernel B: attention, one wave = one (b,h,region) ----------
__global__ __launch_bounds__(256, 4) void lca_kernel(
    const float* __restrict__ q,
    const float* __restrict__ k,
    const float* __restrict__ v,
    const int*   __restrict__ bound,
    float*       __restrict__ out)
{
    const int tid  = threadIdx.x;
    const int wave = tid >> 6;
    const int lane = tid & 63;
    const int grp  = lane >> 3;   // 0..7 : token within 8-token iter
    const int li   = lane & 7;    // 0..7 : dim chunk
    const int dlo  = li << 2;     // low dims dlo..dlo+3 ; high dims +32 (in-lane RoPE pair)

    const int blk = blockIdx.x;   // ((b*NH)+h)*16 + rg
    const int rg  = blk & 15;
    const int h   = (blk >> 4) & (NH - 1);
    const int b   = blk >> 8;
    const int ri  = (rg << 2) + wave;  // region index 0..63 (value ri+1)
    const int p0  = ri << 2;           // first of the region's 4 pools

    const int s   = bound[b * 66 + ri + 1];
    const int e   = bound[b * 66 + ri + 2];
    const int cnt = e - s;

    const size_t bh = (size_t)(b * NH + h);
    const float* kb = k + bh * (size_t)(NT * ND);
    const float* vb = v + bh * (size_t)(NT * ND);
    const float* qb = q + (bh * NP + p0) * ND;

    float l[4] = {0.f, 0.f, 0.f, 0.f};
    float acc[4][8];
    #pragma unroll
    for (int p = 0; p < 4; ++p)
        #pragma unroll
        for (int i = 0; i < 8; ++i) acc[p][i] = 0.f;

    if (cnt > 0) {
        // q for the 4 pools (RoPE at pos 0 == identity), pre-scaled
        float qs[4][8];
        #pragma unroll
        for (int p = 0; p < 4; ++p) {
            const float4 qa = *(const float4*)(qb + p * ND + dlo);
            const float4 qc = *(const float4*)(qb + p * ND + 32 + dlo);
            qs[p][0] = qa.x * QSCALE; qs[p][1] = qa.y * QSCALE;
            qs[p][2] = qa.z * QSCALE; qs[p][3] = qa.w * QSCALE;
            qs[p][4] = qc.x * QSCALE; qs[p][5] = qc.y * QSCALE;
            qs[p][6] = qc.z * QSCALE; qs[p][7] = qc.w * QSCALE;
        }
        float frq[4];
        #pragma unroll
        for (int i = 0; i < 4; ++i)
            frq[i] = exp2f(-INVF_LOG2 * (float)(dlo + i));

        const int iters = (cnt + 7) >> 3;

        // prologue: load iteration 0 (clamped)
        int t0c = min(s + grp, e - 1);
        const float* kp = kb + (size_t)t0c * ND;
        const float* vp = vb + (size_t)t0c * ND;
        float4 ka = *(const float4*)(kp + dlo);
        float4 kc = *(const float4*)(kp + 32 + dlo);
        float4 va = *(const float4*)(vp + dlo);
        float4 vc = *(const float4*)(vp + 32 + dlo);

        for (int it = 0; it < iters; ++it) {
            // prefetch next iteration (clamped; harmless dup on last iter)
            const int tn = min(s + ((it + 1) << 3) + grp, e - 1);
            const float* nkp = kb + (size_t)tn * ND;
            const float* nvp = vb + (size_t)tn * ND;
            const float4 nka = *(const float4*)(nkp + dlo);
            const float4 nkc = *(const float4*)(nkp + 32 + dlo);
            const float4 nva = *(const float4*)(nvp + dlo);
            const float4 nvc = *(const float4*)(nvp + 32 + dlo);

            const int   t     = s + (it << 3) + grp;
            const bool  valid = t < e;
            const float pos   = (float)(min(t, e - 1) - s + RPOS);

            const float klo[4] = {ka.x, ka.y, ka.z, ka.w};
            const float khi[4] = {kc.x, kc.y, kc.z, kc.w};
            float pd0 = 0.f, pd1 = 0.f, pd2 = 0.f, pd3 = 0.f;
            #pragma unroll
            for (int i = 0; i < 4; ++i) {
                float sa, ca;
                __sincosf(pos * frq[i], &sa, &ca);
                const float rlo = klo[i] * ca - khi[i] * sa;
                const float rhi = khi[i] * ca + klo[i] * sa;
                pd0 = fmaf(rlo, qs[0][i], fmaf(rhi, qs[0][i + 4], pd0));
                pd1 = fmaf(rlo, qs[1][i], fmaf(rhi, qs[1][i + 4], pd1));
                pd2 = fmaf(rlo, qs[2][i], fmaf(rhi, qs[2][i + 4], pd2));
                pd3 = fmaf(rlo, qs[3][i], fmaf(rhi, qs[3][i + 4], pd3));
            }
            // reduce over the 8 dim-chunk lanes (bits 0..2)
            #pragma unroll
            for (int m = 1; m <= 4; m <<= 1) {
                pd0 += __shfl_xor(pd0, m);
                pd1 += __shfl_xor(pd1, m);
                pd2 += __shfl_xor(pd2, m);
                pd3 += __shfl_xor(pd3, m);
            }
            const float w0 = valid ? exp2f(pd0) : 0.f;
            const float w1 = valid ? exp2f(pd1) : 0.f;
            const float w2 = valid ? exp2f(pd2) : 0.f;
            const float w3 = valid ? exp2f(pd3) : 0.f;
            l[0] += w0; l[1] += w1; l[2] += w2; l[3] += w3;
            const float vx[8] = {va.x, va.y, va.z, va.w, vc.x, vc.y, vc.z, vc.w};
            #pragma unroll
            for (int i = 0; i < 8; ++i) {
                acc[0][i] = fmaf(w0, vx[i], acc[0][i]);
                acc[1][i] = fmaf(w1, vx[i], acc[1][i]);
                acc[2][i] = fmaf(w2, vx[i], acc[2][i]);
                acc[3][i] = fmaf(w3, vx[i], acc[3][i]);
            }
            ka = nka; kc = nkc; va = nva; vc = nvc;
        }
    } else {
        // empty region: softmax over all -1e30 -> uniform mean of v over T
        for (int t = grp; t < NT; t += 8) {
            const float* vp = vb + (size_t)t * ND;
            const float4 va = *(const float4*)(vp + dlo);
            const float4 vc = *(const float4*)(vp + 32 + dlo);
            acc[0][0] += va.x; acc[0][1] += va.y; acc[0][2] += va.z; acc[0][3] += va.w;
            acc[0][4] += vc.x; acc[0][5] += vc.y; acc[0][6] += vc.z; acc[0][7] += vc.w;
        }
        #pragma unroll
        for (int p = 1; p < 4; ++p)
            #pragma unroll
            for (int i = 0; i < 8; ++i) acc[p][i] = acc[0][i];
        // butterfly below sums 8 groups: pre-divide so l totals NT
        l[0] = l[1] = l[2] = l[3] = (float)NT * 0.125f;
    }

    // butterfly-reduce the 8 token-groups (bits 3..5); all lanes end with totals
    #pragma unroll
    for (int m = 8; m <= 32; m <<= 1) {
        #pragma unroll
        for (int p = 0; p < 4; ++p) {
            l[p] += __shfl_xor(l[p], m);
            #pragma unroll
            for (int i = 0; i < 8; ++i) acc[p][i] += __shfl_xor(acc[p][i], m);
        }
    }

    // groups 0..3 write pool p0+grp (static indexing via predicated unroll)
    #pragma unroll
    for (int p = 0; p < 4; ++p) {
        if (grp == p) {
            const float inv = 1.f / l[p];
            float* op = out + (bh * NP + p0 + p) * ND;
            *(float4*)(op + dlo) = make_float4(acc[p][0] * inv, acc[p][1] * inv,
                                               acc[p][2] * inv, acc[p][3] * inv);
            *(float4*)(op + 32 + dlo) = make_float4(acc[p][4] * inv, acc[p][5] * inv,
                                                    acc[p][6] * inv, acc[p][7] * inv);
        }
    }
}

extern "C" void kernel_launch(void* const* d_in, const int* in_sizes, int n_in,
                              void* d_out, int out_size, void* d_ws, size_t ws_size,
                              hipStream_t stream) {
    (void)in_sizes; (void)n_in; (void)ws_size; (void)out_size;
    const float* q       = (const float*)d_in[0];
    const float* k       = (const float*)d_in[1];
    const float* v       = (const float*)d_in[2];
    const int*   regions = (const int*)d_in[3];
    // d_in[4] t_mask, d_in[5] n_mask all-true; d_in[6] max_n == 64
    float* out   = (float*)d_out;
    int*   bound = (int*)d_ws;   // 4 batches x 66 lower-bounds

    seg_kernel<<<dim3(NB), 1024, 0, stream>>>(regions, bound);
    lca_kernel<<<dim3(NB * NH * (NREG / 4)), 256, 0, stream>>>(q, k, v, bound, out);
}